// Round 1
// 481.723 us; speedup vs baseline: 1.0215x; 1.0215x over previous
//
#include <hip/hip_runtime.h>
#include <hip/hip_bf16.h>

// Gumbel 2:4 masked linear:  out = x @ (W * mask)^T + bias
// Round 3: GEMM rewritten as 256x256 tile, 8 waves, BK=32, 4-deep circular
// LDS pipeline with counted vmcnt (never drains to 0 in the main loop),
// XOR-swizzled LDS chunks (inverse-swizzle on global source, swizzled
// ds_read), s_setprio around the MFMA cluster. Prep kernel unchanged.

#define K_DIM 4096
#define N_DIM 4096
#define M_DIM 4096

typedef unsigned short ushort_t;
typedef __attribute__((ext_vector_type(8))) __bf16 bf16x8;
typedef __attribute__((ext_vector_type(4))) float floatx4;

__device__ __forceinline__ unsigned f2bf(float f) {
    union { float f; unsigned u; } v; v.f = f;
    unsigned u = v.u;
    return (u + 0x7fffu + ((u >> 16) & 1u)) >> 16;   // RNE
}

// patterns packed 4 bits each, idx0 at bits[3:0]: bit i = pattern[idx][i]
#define PAT_PACKED 0x3596ACu

// ---------------- fused prep (unchanged) ----------------
__global__ __launch_bounds__(256) void prep_kernel(
    const float4* __restrict__ x4, uint4* __restrict__ xq4,
    const float4* __restrict__ w4, const float4* __restrict__ cw4,
    const float4* __restrict__ gn4, uint2* __restrict__ wq2) {
    __shared__ float lsum[6144];                     // 1024 blocks x 6 logits = 24KB
    const int tid = threadIdx.x;

    if (blockIdx.x < 8192) {
        int t = blockIdx.x * 256 + tid;
        float4 a = x4[2 * t], b = x4[2 * t + 1];
        uint4 o;
        o.x = f2bf(a.x) | (f2bf(a.y) << 16);
        o.y = f2bf(a.z) | (f2bf(a.w) << 16);
        o.z = f2bf(b.x) | (f2bf(b.y) << 16);
        o.w = f2bf(b.z) | (f2bf(b.w) << 16);
        xq4[t] = o;
        return;
    }

    const int bb = blockIdx.x - 8192;                // [0,4096)
    const float4* g4 = gn4 + (size_t)bb * 1536;
    const float4* c4 = cw4 + (size_t)bb * 1536;
    float4* l4 = (float4*)lsum;
#pragma unroll
    for (int j = 0; j < 6; j++) {                    // coalesced float4
        float4 g = g4[j * 256 + tid], c = c4[j * 256 + tid];
        float4 s;
        s.x = g.x + c.x; s.y = g.y + c.y; s.z = g.z + c.z; s.w = g.w + c.w;
        l4[j * 256 + tid] = s;
    }
    __syncthreads();

#pragma unroll
    for (int sub = 0; sub < 4; sub++) {
        const int pb = sub * 256 + tid;              // local pattern-block
        const float2* lp = (const float2*)&lsum[pb * 6];
        float2 v0 = lp[0], v1 = lp[1], v2 = lp[2];
        float v[6] = {v0.x, v0.y, v1.x, v1.y, v2.x, v2.y};
        int idx = 0; float m = v[0];
#pragma unroll
        for (int i = 1; i < 6; i++)                  // strict > : first-max
            if (v[i] > m) { m = v[i]; idx = i; }
        const unsigned p = (PAT_PACKED >> (idx * 4)) & 0xF;
        const float4 w = w4[(size_t)bb * 1024 + pb];
        uint2 o;
        o.x = ((p & 1) ? f2bf(w.x) : 0u) | (((p >> 1) & 1) ? (f2bf(w.y) << 16) : 0u);
        o.y = (((p >> 2) & 1) ? f2bf(w.z) : 0u) | (((p >> 3) & 1) ? (f2bf(w.w) << 16) : 0u);
        wq2[(size_t)bb * 1024 + pb] = o;
    }
}

// ---------------- bf16 GEMM, C = A * B^T + bias ----------------
// 256x256 tile, 512 thr (8 waves as 2M x 4N, each owns 128x64 of C).
// BK=32, DEPTH=4 circular LDS buffers (4 * (16KB A + 16KB B) = 128KB).
// Pipeline: stage tile t+3 while computing tile t; one s_barrier +
// s_waitcnt vmcnt(8) per K-tile (loads retire in order, so <=8 outstanding
// means tile t's 4 loads have landed for every wave; barrier publishes).
// Swizzle: logical chunk q of row r lives at LDS slot q ^ ((r>>1)&3);
// global_load_lds dest stays lane-linear, the inverse permutation is
// applied to the global source chunk. Every aligned 8-lane ds_read_b128
// group covers 8 distinct 16B granules -> conflict-free.

#define BM 256
#define BN 256
#define BK 32
#define DEPTH 4
#define NT (K_DIM / BK)            // 128
#define TILE_US (BM * BK)          // 8192 ushorts = 16KB

__device__ __forceinline__ void async16(const ushort_t* g, ushort_t* l) {
    __builtin_amdgcn_global_load_lds(
        (const __attribute__((address_space(1))) void*)g,
        (__attribute__((address_space(3))) void*)l, 16, 0, 0);
}

__global__ __launch_bounds__(512, 2) void gemm_bt_kernel(
    const ushort_t* __restrict__ A,   // M x K bf16 (x)
    const ushort_t* __restrict__ B,   // N x K bf16 (masked W)
    const float* __restrict__ bias,
    float* __restrict__ C) {
    __shared__ ushort_t As[DEPTH * TILE_US];   // 64KB
    __shared__ ushort_t Bs[DEPTH * TILE_US];   // 64KB

    const int tid  = threadIdx.x;
    const int lane = tid & 63;
    const int wave = tid >> 6;
    const int wm   = wave >> 2;          // 0..1  (M half)
    const int wn   = wave & 3;           // 0..3  (N quarter)
    const int fr   = lane & 15;
    const int q    = lane >> 4;
    const int bm   = blockIdx.y * BM;
    const int bn   = blockIdx.x * BN;

    // ---- staging addresses ----
    // slot s = i*512 + tid; row = s>>2 in [0,256), slot-chunk = s&3.
    // slot (row, s) must hold logical chunk s ^ ((row>>1)&3).
    const int srow = tid >> 2;                       // 0..127 (i adds 128)
    const int sch  = (tid & 3) ^ ((srow >> 1) & 3);  // same for i=1 (128>>1 % 4 == 0)
    const ushort_t* Ag0 = A + (size_t)(bm + srow) * K_DIM + sch * 8;
    const ushort_t* Ag1 = A + (size_t)(bm + 128 + srow) * K_DIM + sch * 8;
    const ushort_t* Bg0 = B + (size_t)(bn + srow) * K_DIM + sch * 8;
    const ushort_t* Bg1 = B + (size_t)(bn + 128 + srow) * K_DIM + sch * 8;
    ushort_t* lA = &As[tid * 8];                     // lane-linear dest
    ushort_t* lB = &Bs[tid * 8];

    // ---- fragment-read offsets (ushort units), swizzled chunk ----
    // reader wants logical chunk q of row r -> reads slot q ^ ((r>>1)&3);
    // (r>>1)&3 == (fr>>1)&3 for all r in this wave's ranges.
    const int ch = q ^ ((fr >> 1) & 3);
    int offA[8], offB[4];
#pragma unroll
    for (int r = 0; r < 8; ++r)
        offA[r] = (wm * 128 + r * 16 + fr) * BK + ch * 8;
#pragma unroll
    for (int c = 0; c < 4; ++c)
        offB[c] = (wn * 64 + c * 16 + fr) * BK + ch * 8;

    floatx4 acc[8][4] = {};

#define STAGE(t) do {                                               \
        const int _b = (t) & (DEPTH - 1);                           \
        const size_t _ko = (size_t)(t) * BK;                        \
        async16(Ag0 + _ko, lA + _b * TILE_US);                      \
        async16(Ag1 + _ko, lA + _b * TILE_US + 4096);               \
        async16(Bg0 + _ko, lB + _b * TILE_US);                      \
        async16(Bg1 + _ko, lB + _b * TILE_US + 4096);               \
    } while (0)

#define COMPUTE(t) do {                                             \
        const ushort_t* _pa = &As[((t) & (DEPTH - 1)) * TILE_US];   \
        const ushort_t* _pb = &Bs[((t) & (DEPTH - 1)) * TILE_US];   \
        bf16x8 _a[8], _bv[4];                                       \
        _Pragma("unroll")                                           \
        for (int r = 0; r < 8; ++r)                                 \
            _a[r] = *(const bf16x8*)&_pa[offA[r]];                  \
        _Pragma("unroll")                                           \
        for (int c = 0; c < 4; ++c)                                 \
            _bv[c] = *(const bf16x8*)&_pb[offB[c]];                 \
        __builtin_amdgcn_s_setprio(1);                              \
        _Pragma("unroll")                                           \
        for (int r = 0; r < 8; ++r)                                 \
            _Pragma("unroll")                                       \
            for (int c = 0; c < 4; ++c)                             \
                acc[r][c] = __builtin_amdgcn_mfma_f32_16x16x32_bf16(\
                    _a[r], _bv[c], acc[r][c], 0, 0, 0);             \
        __builtin_amdgcn_s_setprio(0);                              \
    } while (0)

    // prologue: 3 tiles in flight
    STAGE(0); STAGE(1); STAGE(2);

    // main loop: wait to <=8 outstanding loads (tile t landed), publish via
    // barrier, prefetch t+3 into the buffer freed at t-1, compute t.
    for (int t = 0; t < NT - 2; ++t) {
        asm volatile("s_waitcnt vmcnt(8)\n\ts_barrier" ::: "memory");
        if (t + 3 < NT) STAGE(t + 3);
        COMPUTE(t);
    }
    // epilogue: drain the last two tiles
    asm volatile("s_waitcnt vmcnt(4)\n\ts_barrier" ::: "memory");
    COMPUTE(NT - 2);
    asm volatile("s_waitcnt vmcnt(0)\n\ts_barrier" ::: "memory");
    COMPUTE(NT - 1);

#undef STAGE
#undef COMPUTE

    // epilogue: D col = lane&15, row = q*4 + reg  (verified mapping)
#pragma unroll
    for (int c = 0; c < 4; ++c) {
        const int gcol = bn + wn * 64 + c * 16 + fr;
        const float bv = bias[gcol];
#pragma unroll
        for (int r = 0; r < 8; ++r) {
            const int grow = bm + wm * 128 + r * 16 + q * 4;
#pragma unroll
            for (int reg = 0; reg < 4; ++reg)
                C[(size_t)(grow + reg) * N_DIM + gcol] = acc[r][c][reg] + bv;
        }
    }
}

extern "C" void kernel_launch(void* const* d_in, const int* in_sizes, int n_in,
                              void* d_out, int out_size, void* d_ws, size_t ws_size,
                              hipStream_t stream) {
    const float* x    = (const float*)d_in[0];
    const float* w    = (const float*)d_in[1];
    const float* bias = (const float*)d_in[2];
    const float* cw   = (const float*)d_in[3];
    const float* gn   = (const float*)d_in[4];
    ushort_t* xq = (ushort_t*)d_ws;                       // 32 MiB
    ushort_t* wq = xq + (size_t)M_DIM * K_DIM;            // 32 MiB
    float* out = (float*)d_out;

    prep_kernel<<<12288, 256, 0, stream>>>(
        (const float4*)x, (uint4*)xq, (const float4*)w,
        (const float4*)cw, (const float4*)gn, (uint2*)wq);
    dim3 grid(N_DIM / BN, M_DIM / BM);
    gemm_bt_kernel<<<grid, 512, 0, stream>>>(xq, wq, bias, out);
}

// Round 2
// 456.477 us; speedup vs baseline: 1.0780x; 1.0553x over previous
//
#include <hip/hip_runtime.h>
#include <hip/hip_bf16.h>

// Gumbel 2:4 masked linear:  out = x @ (W * mask)^T + bias
// Round 4: GEMM ported to the m201-style 256x256 8-phase schedule:
//   BK=64, 2 K-tiles per iteration, 8 phases each {ds-read subtile | stage
//   half-tile | barrier | lgkmcnt(0) | setprio(1) 16xMFMA setprio(0) | barrier},
//   counted vmcnt(4) only at phases 4 and 8 (never drained in main loop),
//   XOR chunk swizzle (inverse on global src, linear global_load_lds dest),
//   XCD-chunked block swizzle. Prep kernel unchanged.

#define K_DIM 4096
#define N_DIM 4096
#define M_DIM 4096

typedef unsigned short ushort_t;
typedef __attribute__((ext_vector_type(8))) __bf16 bf16x8;
typedef __attribute__((ext_vector_type(4))) float floatx4;

__device__ __forceinline__ unsigned f2bf(float f) {
    union { float f; unsigned u; } v; v.f = f;
    unsigned u = v.u;
    return (u + 0x7fffu + ((u >> 16) & 1u)) >> 16;   // RNE
}

// patterns packed 4 bits each, idx0 at bits[3:0]: bit i = pattern[idx][i]
#define PAT_PACKED 0x3596ACu

// ---------------- fused prep (unchanged) ----------------
__global__ __launch_bounds__(256) void prep_kernel(
    const float4* __restrict__ x4, uint4* __restrict__ xq4,
    const float4* __restrict__ w4, const float4* __restrict__ cw4,
    const float4* __restrict__ gn4, uint2* __restrict__ wq2) {
    __shared__ float lsum[6144];                     // 1024 blocks x 6 logits = 24KB
    const int tid = threadIdx.x;

    if (blockIdx.x < 8192) {
        int t = blockIdx.x * 256 + tid;
        float4 a = x4[2 * t], b = x4[2 * t + 1];
        uint4 o;
        o.x = f2bf(a.x) | (f2bf(a.y) << 16);
        o.y = f2bf(a.z) | (f2bf(a.w) << 16);
        o.z = f2bf(b.x) | (f2bf(b.y) << 16);
        o.w = f2bf(b.z) | (f2bf(b.w) << 16);
        xq4[t] = o;
        return;
    }

    const int bb = blockIdx.x - 8192;                // [0,4096)
    const float4* g4 = gn4 + (size_t)bb * 1536;
    const float4* c4 = cw4 + (size_t)bb * 1536;
    float4* l4 = (float4*)lsum;
#pragma unroll
    for (int j = 0; j < 6; j++) {                    // coalesced float4
        float4 g = g4[j * 256 + tid], c = c4[j * 256 + tid];
        float4 s;
        s.x = g.x + c.x; s.y = g.y + c.y; s.z = g.z + c.z; s.w = g.w + c.w;
        l4[j * 256 + tid] = s;
    }
    __syncthreads();

#pragma unroll
    for (int sub = 0; sub < 4; sub++) {
        const int pb = sub * 256 + tid;              // local pattern-block
        const float2* lp = (const float2*)&lsum[pb * 6];
        float2 v0 = lp[0], v1 = lp[1], v2 = lp[2];
        float v[6] = {v0.x, v0.y, v1.x, v1.y, v2.x, v2.y};
        int idx = 0; float m = v[0];
#pragma unroll
        for (int i = 1; i < 6; i++)                  // strict > : first-max
            if (v[i] > m) { m = v[i]; idx = i; }
        const unsigned p = (PAT_PACKED >> (idx * 4)) & 0xF;
        const float4 w = w4[(size_t)bb * 1024 + pb];
        uint2 o;
        o.x = ((p & 1) ? f2bf(w.x) : 0u) | (((p >> 1) & 1) ? (f2bf(w.y) << 16) : 0u);
        o.y = (((p >> 2) & 1) ? f2bf(w.z) : 0u) | (((p >> 3) & 1) ? (f2bf(w.w) << 16) : 0u);
        wq2[(size_t)bb * 1024 + pb] = o;
    }
}

// ---------------- bf16 GEMM, C = A * B^T + bias, 8-phase schedule ----------------
// 256x256 tile, 512 thr (8 waves 2M x 4N), per-wave C = 128x64.
// BK=64, 2 K-tiles resident (2 x 64KB), each split into half-tile regions:
//   A halves by row bit6 (quadrant qm), B halves by row bit5 (quadrant qn),
// so each phase's C-quadrant reads exactly one A-half and one B-half and the
// half freed by phase p is restaged in a later phase of the same iteration.
// Snake order (0,0)(0,1)(1,1)(1,0) per K-tile; 16 MFMA per phase.
// Staging: 1 half-tile (2 x global_load_lds_dwordx4) per phase; vmcnt(4) at
// phases 4 and 8 guarantees the next K-tile landed with 2 half-tiles still
// in flight. Chunk swizzle: LDS slot c of row lr holds global chunk
// c ^ (lr&7); applied inverse on the global source (linear LDS dest).

#define BK 64
#define ITERS 32            // 64 K-tiles, 2 per iteration

__device__ __forceinline__ void async16(const ushort_t* g, ushort_t* l) {
    __builtin_amdgcn_global_load_lds(
        (const __attribute__((address_space(1))) void*)g,
        (__attribute__((address_space(3))) void*)l, 16, 0, 0);
}

__global__ __launch_bounds__(512, 2) void gemm_bt_kernel(
    const ushort_t* __restrict__ A,   // M x K bf16 (x)
    const ushort_t* __restrict__ B,   // N x K bf16 (masked W)
    const float* __restrict__ bias,
    float* __restrict__ C) {
    __shared__ ushort_t As[32768];    // 2 dbuf x 2 half x 128 rows x 64k = 64KB
    __shared__ ushort_t Bs[32768];    // 64KB

    const int tid  = threadIdx.x;
    const int lane = tid & 63;
    const int wave = tid >> 6;
    const int wm   = wave >> 2;       // 0..1
    const int wn   = wave & 3;        // 0..3
    const int fr   = lane & 15;
    const int q    = lane >> 4;
    const int f7   = fr & 7;

    // XCD-chunked swizzle: 256 blocks, 32 contiguous per XCD (A-panel = 4MB = L2)
    const int fid = blockIdx.y * 16 + blockIdx.x;
    const int swz = (fid & 7) * 32 + (fid >> 3);
    const int bm  = (swz >> 4) * 256;
    const int bn  = (swz & 15) * 256;

    // ---- staging bases ----
    // slot s = j*512 + tid, lr = s>>3 (0..127), c = s&7; LDS holds global
    // chunk c ^ (lr&7).  lr&7 == (tid>>3)&7 for both j.
    const int u  = tid >> 3;
    const int cs = (tid & 7) ^ (u & 7);
    const ushort_t* Abase = A + (size_t)(bm + u) * K_DIM + cs * 8;
    const ushort_t* Bbase = B + (size_t)(bn + (u & 31) + ((u >> 5) << 6)) * K_DIM + cs * 8;
    ushort_t* lAd = &As[tid * 8];
    ushort_t* lBd = &Bs[tid * 8];

    // ---- read offsets (ushort units) ----
    const int aOff = wm * 4096 + fr * 64;    // local row lr = wm*64 + r*16 + fr
    const int bOff = wn * 2048 + fr * 64;    // local row lr = wn*32 + c*16 + fr
    const int c0   = (q ^ f7) * 8;           // k-half 0 chunk (swizzled)
    const int c1   = ((4 + q) ^ f7) * 8;     // k-half 1 chunk

    bf16x8 a[4][2], b[2][2];
    floatx4 acc[8][4] = {};

#define STA(db_, h_, t_) do {                                                   \
        async16(Abase + (size_t)((h_) * 64      ) * K_DIM + (size_t)(t_) * BK,  \
                lAd + (db_) * 16384 + (h_) * 8192);                             \
        async16(Abase + (size_t)((h_) * 64 + 128) * K_DIM + (size_t)(t_) * BK,  \
                lAd + (db_) * 16384 + (h_) * 8192 + 4096);                      \
    } while (0)
#define STB(db_, h_, t_) do {                                                   \
        async16(Bbase + (size_t)((h_) * 32      ) * K_DIM + (size_t)(t_) * BK,  \
                lBd + (db_) * 16384 + (h_) * 8192);                             \
        async16(Bbase + (size_t)((h_) * 32 + 128) * K_DIM + (size_t)(t_) * BK,  \
                lBd + (db_) * 16384 + (h_) * 8192 + 4096);                      \
    } while (0)

#define LDA(db_, qm_) do {                                                      \
        _Pragma("unroll")                                                       \
        for (int r = 0; r < 4; ++r) {                                           \
            const int o = (db_) * 16384 + (qm_) * 8192 + aOff + r * 1024;       \
            a[r][0] = *(const bf16x8*)&As[o + c0];                              \
            a[r][1] = *(const bf16x8*)&As[o + c1];                              \
        } } while (0)
#define LDB(db_, qn_) do {                                                      \
        _Pragma("unroll")                                                       \
        for (int c = 0; c < 2; ++c) {                                           \
            const int o = (db_) * 16384 + (qn_) * 8192 + bOff + c * 1024;       \
            b[c][0] = *(const bf16x8*)&Bs[o + c0];                              \
            b[c][1] = *(const bf16x8*)&Bs[o + c1];                              \
        } } while (0)

#define MM(qm_, qn_) do {                                                       \
        __builtin_amdgcn_s_setprio(1);                                          \
        _Pragma("unroll")                                                       \
        for (int kh = 0; kh < 2; ++kh)                                          \
            _Pragma("unroll")                                                   \
            for (int r = 0; r < 4; ++r)                                         \
                _Pragma("unroll")                                               \
                for (int c = 0; c < 2; ++c)                                     \
                    acc[(qm_) * 4 + r][(qn_) * 2 + c] =                         \
                        __builtin_amdgcn_mfma_f32_16x16x32_bf16(                \
                            a[r][kh], b[c][kh],                                 \
                            acc[(qm_) * 4 + r][(qn_) * 2 + c], 0, 0, 0);        \
        __builtin_amdgcn_s_setprio(0);                                          \
    } while (0)

#define PH_OPEN do {                                                            \
        __builtin_amdgcn_s_barrier();                                           \
        asm volatile("s_waitcnt lgkmcnt(0)" ::: "memory");                      \
        __builtin_amdgcn_sched_barrier(0);                                      \
    } while (0)
#define PH_CLOSE do {                                                           \
        __builtin_amdgcn_sched_barrier(0);                                      \
        __builtin_amdgcn_s_barrier();                                           \
    } while (0)
#define VM4 asm volatile("s_waitcnt vmcnt(4)" ::: "memory")
#define VM0 asm volatile("s_waitcnt vmcnt(0)" ::: "memory")

    // prologue: tile 0 (all 4 halves) + tile 1's Ah0,Bh1; wait tile 0 landed
    STA(0, 0, 0); STA(0, 1, 0); STB(0, 0, 0); STB(0, 1, 0);
    STA(1, 0, 1); STB(1, 1, 1);
    VM4;
    __builtin_amdgcn_s_barrier();

#pragma unroll 1
    for (int I = 0; I < ITERS - 1; ++I) {
        const int t1 = 2 * I + 1, t2 = 2 * I + 2, t3 = 2 * I + 3;
        // phases 1-4: compute tile 2I (buf0), snake (0,0)(0,1)(1,1)(1,0)
        LDA(0, 0); LDB(0, 0); STA(1, 1, t1); PH_OPEN; MM(0, 0); PH_CLOSE;
        LDB(0, 1);            STB(1, 0, t1); PH_OPEN; MM(0, 1); PH_CLOSE;
        LDA(0, 1);            STA(0, 0, t2); PH_OPEN; MM(1, 1); PH_CLOSE;
        LDB(0, 0);            STB(0, 1, t2); PH_OPEN; MM(1, 0); VM4; PH_CLOSE;
        // phases 5-8: compute tile 2I+1 (buf1)
        LDA(1, 0); LDB(1, 0); STA(0, 1, t2); PH_OPEN; MM(0, 0); PH_CLOSE;
        LDB(1, 1);            STB(0, 0, t2); PH_OPEN; MM(0, 1); PH_CLOSE;
        LDA(1, 1);            STA(1, 0, t3); PH_OPEN; MM(1, 1); PH_CLOSE;
        LDB(1, 0);            STB(1, 1, t3); PH_OPEN; MM(1, 0); VM4; PH_CLOSE;
    }
    // peeled final iteration (tiles 62,63): finish staging 63, then drain once
    LDA(0, 0); LDB(0, 0); STA(1, 1, 63); PH_OPEN; MM(0, 0); PH_CLOSE;
    LDB(0, 1);            STB(1, 0, 63); PH_OPEN; MM(0, 1); PH_CLOSE;
    LDA(0, 1);                           PH_OPEN; MM(1, 1); PH_CLOSE;
    LDB(0, 0);                           PH_OPEN; MM(1, 0); VM0; PH_CLOSE;
    LDA(1, 0); LDB(1, 0);                PH_OPEN; MM(0, 0); PH_CLOSE;
    LDB(1, 1);                           PH_OPEN; MM(0, 1); PH_CLOSE;
    LDA(1, 1);                           PH_OPEN; MM(1, 1); PH_CLOSE;
    LDB(1, 0);                           PH_OPEN; MM(1, 0); PH_CLOSE;

#undef STA
#undef STB
#undef LDA
#undef LDB
#undef MM
#undef PH_OPEN
#undef PH_CLOSE
#undef VM4
#undef VM0

    // epilogue: D col = lane&15, row = q*4 + reg (verified mapping)
#pragma unroll
    for (int c = 0; c < 4; ++c) {
        const int gcol = bn + wn * 64 + c * 16 + fr;
        const float bv = bias[gcol];
#pragma unroll
        for (int r = 0; r < 8; ++r) {
            const int grow = bm + wm * 128 + r * 16 + q * 4;
#pragma unroll
            for (int reg = 0; reg < 4; ++reg)
                C[(size_t)(grow + reg) * N_DIM + gcol] = acc[r][c][reg] + bv;
        }
    }
}

extern "C" void kernel_launch(void* const* d_in, const int* in_sizes, int n_in,
                              void* d_out, int out_size, void* d_ws, size_t ws_size,
                              hipStream_t stream) {
    const float* x    = (const float*)d_in[0];
    const float* w    = (const float*)d_in[1];
    const float* bias = (const float*)d_in[2];
    const float* cw   = (const float*)d_in[3];
    const float* gn   = (const float*)d_in[4];
    ushort_t* xq = (ushort_t*)d_ws;                       // 32 MiB
    ushort_t* wq = xq + (size_t)M_DIM * K_DIM;            // 32 MiB
    float* out = (float*)d_out;

    prep_kernel<<<12288, 256, 0, stream>>>(
        (const float4*)x, (uint4*)xq, (const float4*)w,
        (const float4*)cw, (const float4*)gn, (uint2*)wq);
    dim3 grid(N_DIM / 256, M_DIM / 256);
    gemm_bt_kernel<<<grid, 512, 0, stream>>>(xq, wq, bias, out);
}

// Round 3
// 443.375 us; speedup vs baseline: 1.1098x; 1.0296x over previous
//
#include <hip/hip_runtime.h>
#include <hip/hip_bf16.h>

// Gumbel 2:4 masked linear:  out = x @ (W * mask)^T + bias
// Round 5: 8-phase GEMM with REGISTER-pipelined fragments (ds_reads issued one
// phase ahead, counted lgkmcnt(N) at phase open), snake order (0,0)(1,0)(1,1)(0,1)
// so 2 A-sets + 2 B-sets suffice and every operand is LDS-read exactly once per
// K-tile (24 b128/wave/K-tile). Staging: 1 half-tile per phase conveyor,
// stage->read distance >= 4 phases, vmcnt(6) per phase (never 0 in main loop).
// Prep split into two kernels for per-dispatch profiling.

#define K_DIM 4096
#define N_DIM 4096
#define M_DIM 4096

typedef unsigned short ushort_t;
typedef __attribute__((ext_vector_type(8))) __bf16 bf16x8;
typedef __attribute__((ext_vector_type(4))) float floatx4;

__device__ __forceinline__ unsigned f2bf(float f) {
    union { float f; unsigned u; } v; v.f = f;
    unsigned u = v.u;
    return (u + 0x7fffu + ((u >> 16) & 1u)) >> 16;   // RNE
}

// patterns packed 4 bits each, idx0 at bits[3:0]: bit i = pattern[idx][i]
#define PAT_PACKED 0x3596ACu

// ---------------- prep A: x fp32 -> bf16 (coalesced, 8 elem/thread) ----------------
__global__ __launch_bounds__(256) void xcvt_kernel(
    const float4* __restrict__ x4, uint4* __restrict__ xq4) {
    int t = blockIdx.x * 256 + threadIdx.x;
    float4 a = x4[2 * t], b = x4[2 * t + 1];
    uint4 o;
    o.x = f2bf(a.x) | (f2bf(a.y) << 16);
    o.y = f2bf(a.z) | (f2bf(a.w) << 16);
    o.z = f2bf(b.x) | (f2bf(b.y) << 16);
    o.w = f2bf(b.z) | (f2bf(b.w) << 16);
    xq4[t] = o;
}

// ---------------- prep B: gumbel argmax -> masked W -> bf16 ----------------
__global__ __launch_bounds__(256) void mask_kernel(
    const float4* __restrict__ w4, const float4* __restrict__ cw4,
    const float4* __restrict__ gn4, uint2* __restrict__ wq2) {
    __shared__ float lsum[6144];                     // 1024 blocks x 6 logits = 24KB
    const int tid = threadIdx.x;
    const int bb = blockIdx.x;                       // [0,4096)
    const float4* g4 = gn4 + (size_t)bb * 1536;
    const float4* c4 = cw4 + (size_t)bb * 1536;
    float4* l4 = (float4*)lsum;
#pragma unroll
    for (int j = 0; j < 6; j++) {                    // coalesced float4
        float4 g = g4[j * 256 + tid], c = c4[j * 256 + tid];
        float4 s;
        s.x = g.x + c.x; s.y = g.y + c.y; s.z = g.z + c.z; s.w = g.w + c.w;
        l4[j * 256 + tid] = s;
    }
    __syncthreads();

#pragma unroll
    for (int sub = 0; sub < 4; sub++) {
        const int pb = sub * 256 + tid;              // local pattern-block
        const float2* lp = (const float2*)&lsum[pb * 6];
        float2 v0 = lp[0], v1 = lp[1], v2 = lp[2];
        float v[6] = {v0.x, v0.y, v1.x, v1.y, v2.x, v2.y};
        int idx = 0; float m = v[0];
#pragma unroll
        for (int i = 1; i < 6; i++)                  // strict > : first-max
            if (v[i] > m) { m = v[i]; idx = i; }
        const unsigned p = (PAT_PACKED >> (idx * 4)) & 0xF;
        const float4 w = w4[(size_t)bb * 1024 + pb];
        uint2 o;
        o.x = ((p & 1) ? f2bf(w.x) : 0u) | (((p >> 1) & 1) ? (f2bf(w.y) << 16) : 0u);
        o.y = (((p >> 2) & 1) ? f2bf(w.z) : 0u) | (((p >> 3) & 1) ? (f2bf(w.w) << 16) : 0u);
        wq2[(size_t)bb * 1024 + pb] = o;
    }
}

// ---------------- bf16 GEMM, C = A * B^T + bias ----------------
// 256x256 tile, 512 thr (8 waves 2M x 4N), per-wave C = 128x64. BK=64,
// 2 K-tiles resident (buf0/buf1, 4 half-regions each of 8KB ushorts=16KB).
//
// Phase table (steady iteration I, t=2I; LD feeds MFMA of NEXT phase):
//  ph | LD (ds_read, count)       | STAGE (conveyor)   | lgkm | MFMA (set use)
//   1 | a1<-buf0.Ah1   [8]        | buf1.Ah1 (t+1)     |  8   | (0,0) a0,b0
//   2 | b1<-buf0.Bh1   [4]        | buf1.Bh1 (t+1)     |  4   | (1,0) a1,b0
//   3 | --                        | buf0.Bh0 (t+2)     |  0   | (1,1) a1,b1
//   4 | a1<-buf1.Ah0,b0<-buf1.Bh0 | buf0.Ah0 (t+2)     | 12   | (0,1) a0,b1
//   5 | a0<-buf1.Ah1   [8]        | buf0.Ah1 (t+2)     |  8   | (0,0) a1,b0
//   6 | b1<-buf1.Bh1   [4]        | buf0.Bh1 (t+2)     |  4   | (1,0) a0,b0
//   7 | --                        | buf1.Bh0 (t+3)     |  0   | (1,1) a0,b1
//   8 | a0<-buf0.Ah0,b0<-buf0.Bh0 | buf1.Ah0 (t+3)     | 12   | (0,1) a1,b1
// All stage->first-LD distances >= 4 phases; vmcnt(6) AFTER each stage leaves
// last 3 half-tiles in flight => stages <= p-4 are cross-wave published at the
// p-1 closing barrier before any LD at p reads them. Region reuse distances
// all >= lastLD+2 (reads drained by counted lgkm + barrier before overwrite).
// Chunk swizzle: LDS slot c of row lr holds global chunk c ^ (lr&7), applied
// inverse on the global source (global_load_lds dest stays lane-linear).

#define BK 64

__device__ __forceinline__ void async16(const ushort_t* g, ushort_t* l) {
    __builtin_amdgcn_global_load_lds(
        (const __attribute__((address_space(1))) void*)g,
        (__attribute__((address_space(3))) void*)l, 16, 0, 0);
}

__global__ __launch_bounds__(512, 2) void gemm_bt_kernel(
    const ushort_t* __restrict__ A,   // M x K bf16 (x)
    const ushort_t* __restrict__ B,   // N x K bf16 (masked W)
    const float* __restrict__ bias,
    float* __restrict__ C) {
    __shared__ ushort_t As[32768];    // 2 dbuf x 2 half x 8192 ushorts = 64KB
    __shared__ ushort_t Bs[32768];    // 64KB

    const int tid  = threadIdx.x;
    const int lane = tid & 63;
    const int wave = tid >> 6;
    const int wm   = wave >> 2;       // 0..1
    const int wn   = wave & 3;        // 0..3
    const int fr   = lane & 15;
    const int q    = lane >> 4;
    const int f7   = fr & 7;

    // XCD-chunked swizzle: 256 blocks, 32 contiguous per XCD
    const int fid = blockIdx.y * 16 + blockIdx.x;
    const int swz = (fid & 7) * 32 + (fid >> 3);
    const int bm  = (swz >> 4) * 256;
    const int bn  = (swz & 15) * 256;

    // staging: slot s = j*512+tid, lr = s>>3, c = s&7; holds global chunk c^(lr&7)
    const int u  = tid >> 3;
    const int cs = (tid & 7) ^ (u & 7);
    const ushort_t* Abase = A + (size_t)(bm + u) * K_DIM + cs * 8;
    const ushort_t* Bbase = B + (size_t)(bn + (u & 31) + ((u >> 5) << 6)) * K_DIM + cs * 8;
    ushort_t* lAd = &As[tid * 8];
    ushort_t* lBd = &Bs[tid * 8];

    // read offsets (ushort units)
    const int aOff = wm * 4096 + fr * 64;
    const int bOff = wn * 2048 + fr * 64;
    const int c0   = (q ^ f7) * 8;
    const int c1   = ((4 + q) ^ f7) * 8;

    bf16x8 a0[4][2], a1[4][2], b0[2][2], b1[2][2];
    floatx4 acc[8][4] = {};

#define STA(db_, h_, t_) do {                                                   \
        async16(Abase + (size_t)((h_) * 64      ) * K_DIM + (size_t)(t_) * BK,  \
                lAd + (db_) * 16384 + (h_) * 8192);                             \
        async16(Abase + (size_t)((h_) * 64 + 128) * K_DIM + (size_t)(t_) * BK,  \
                lAd + (db_) * 16384 + (h_) * 8192 + 4096);                      \
    } while (0)
#define STB(db_, h_, t_) do {                                                   \
        async16(Bbase + (size_t)((h_) * 32      ) * K_DIM + (size_t)(t_) * BK,  \
                lBd + (db_) * 16384 + (h_) * 8192);                             \
        async16(Bbase + (size_t)((h_) * 32 + 128) * K_DIM + (size_t)(t_) * BK,  \
                lBd + (db_) * 16384 + (h_) * 8192 + 4096);                      \
    } while (0)

#define LDA_S(dst_, db_, qm_) do {                                              \
        _Pragma("unroll")                                                       \
        for (int r = 0; r < 4; ++r) {                                           \
            const int o = (db_) * 16384 + (qm_) * 8192 + aOff + r * 1024;       \
            dst_[r][0] = *(const bf16x8*)&As[o + c0];                           \
            dst_[r][1] = *(const bf16x8*)&As[o + c1];                           \
        } } while (0)
#define LDB_S(dst_, db_, h_) do {                                               \
        _Pragma("unroll")                                                       \
        for (int c = 0; c < 2; ++c) {                                           \
            const int o = (db_) * 16384 + (h_) * 8192 + bOff + c * 1024;        \
            dst_[c][0] = *(const bf16x8*)&Bs[o + c0];                           \
            dst_[c][1] = *(const bf16x8*)&Bs[o + c1];                           \
        } } while (0)

#define MMQ(qm_, qn_, A_, B_) do {                                              \
        __builtin_amdgcn_s_setprio(1);                                          \
        _Pragma("unroll")                                                       \
        for (int kh = 0; kh < 2; ++kh)                                          \
            _Pragma("unroll")                                                   \
            for (int r = 0; r < 4; ++r)                                         \
                _Pragma("unroll")                                               \
                for (int c = 0; c < 2; ++c)                                     \
                    acc[(qm_) * 4 + r][(qn_) * 2 + c] =                         \
                        __builtin_amdgcn_mfma_f32_16x16x32_bf16(                \
                            A_[r][kh], B_[c][kh],                               \
                            acc[(qm_) * 4 + r][(qn_) * 2 + c], 0, 0, 0);        \
        __builtin_amdgcn_s_setprio(0);                                          \
    } while (0)

#define VMW(N_) asm volatile("s_waitcnt vmcnt(" #N_ ")" ::: "memory")
#define SO(N_) do {                                                             \
        __builtin_amdgcn_sched_barrier(0);                                      \
        __builtin_amdgcn_s_barrier();                                           \
        asm volatile("s_waitcnt lgkmcnt(" #N_ ")" ::: "memory");                \
        __builtin_amdgcn_sched_barrier(0);                                      \
    } while (0)
#define PE do {                                                                 \
        __builtin_amdgcn_sched_barrier(0);                                      \
        __builtin_amdgcn_s_barrier();                                           \
    } while (0)

    // prologue: stage buf0 all 4 halves + buf1.{Bh0,Ah0}; publish buf0; pre-LD
    STA(0, 0, 0); STB(0, 0, 0); STA(0, 1, 0); STB(0, 1, 0);
    STB(1, 0, 1); STA(1, 0, 1);
    VMW(4);                               // buf0's 8 loads landed (buf1 pair in flight)
    __builtin_amdgcn_sched_barrier(0);
    __builtin_amdgcn_s_barrier();
    LDA_S(a0, 0, 0); LDB_S(b0, 0, 0);     // 12 reads; drained by ph1's lgkm(8)

#pragma unroll 1
    for (int I = 0; I < 31; ++I) {
        const int t1 = 2 * I + 1, t2 = 2 * I + 2, t3 = 2 * I + 3;
        LDA_S(a1, 0, 1);                  STA(1, 1, t1); VMW(6); SO(8);  MMQ(0, 0, a0, b0); PE;
        LDB_S(b1, 0, 1);                  STB(1, 1, t1); VMW(6); SO(4);  MMQ(1, 0, a1, b0); PE;
                                          STB(0, 0, t2); VMW(6); SO(0);  MMQ(1, 1, a1, b1); PE;
        LDA_S(a1, 1, 0); LDB_S(b0, 1, 0); STA(0, 0, t2); VMW(6); SO(12); MMQ(0, 1, a0, b1); PE;
        LDA_S(a0, 1, 1);                  STA(0, 1, t2); VMW(6); SO(8);  MMQ(0, 0, a1, b0); PE;
        LDB_S(b1, 1, 1);                  STB(0, 1, t2); VMW(6); SO(4);  MMQ(1, 0, a0, b0); PE;
                                          STB(1, 0, t3); VMW(6); SO(0);  MMQ(1, 1, a0, b1); PE;
        LDA_S(a0, 0, 0); LDB_S(b0, 0, 0); STA(1, 0, t3); VMW(6); SO(12); MMQ(0, 1, a1, b1); PE;
    }
    // peeled final iteration (tiles 62 in buf0, 63 in buf1)
    LDA_S(a1, 0, 1);                  STA(1, 1, 63); VMW(6); SO(8);  MMQ(0, 0, a0, b0); PE;
    LDB_S(b1, 0, 1);                  STB(1, 1, 63); VMW(6); SO(4);  MMQ(1, 0, a1, b0); PE;
                                                     VMW(4); SO(0);  MMQ(1, 1, a1, b1); PE;
    LDA_S(a1, 1, 0); LDB_S(b0, 1, 0);                VMW(0); SO(12); MMQ(0, 1, a0, b1); PE;
    LDA_S(a0, 1, 1);                                         SO(8);  MMQ(0, 0, a1, b0); PE;
    LDB_S(b1, 1, 1);                                         SO(4);  MMQ(1, 0, a0, b0); PE;
                                                             SO(0);  MMQ(1, 1, a0, b1); PE;
                                                             SO(0);  MMQ(0, 1, a1, b1); PE;

#undef STA
#undef STB
#undef LDA_S
#undef LDB_S
#undef MMQ
#undef VMW
#undef SO
#undef PE

    // epilogue: D col = lane&15, row = q*4 + reg (verified mapping)
#pragma unroll
    for (int c = 0; c < 4; ++c) {
        const int gcol = bn + wn * 64 + c * 16 + fr;
        const float bv = bias[gcol];
#pragma unroll
        for (int r = 0; r < 8; ++r) {
            const int grow = bm + wm * 128 + r * 16 + q * 4;
#pragma unroll
            for (int reg = 0; reg < 4; ++reg)
                C[(size_t)(grow + reg) * N_DIM + gcol] = acc[r][c][reg] + bv;
        }
    }
}

extern "C" void kernel_launch(void* const* d_in, const int* in_sizes, int n_in,
                              void* d_out, int out_size, void* d_ws, size_t ws_size,
                              hipStream_t stream) {
    const float* x    = (const float*)d_in[0];
    const float* w    = (const float*)d_in[1];
    const float* bias = (const float*)d_in[2];
    const float* cw   = (const float*)d_in[3];
    const float* gn   = (const float*)d_in[4];
    ushort_t* xq = (ushort_t*)d_ws;                       // 32 MiB
    ushort_t* wq = xq + (size_t)M_DIM * K_DIM;            // 32 MiB
    float* out = (float*)d_out;

    xcvt_kernel<<<8192, 256, 0, stream>>>((const float4*)x, (uint4*)xq);
    mask_kernel<<<4096, 256, 0, stream>>>(
        (const float4*)w, (const float4*)cw, (const float4*)gn, (uint2*)wq);
    dim3 grid(N_DIM / 256, M_DIM / 256);
    gemm_bt_kernel<<<grid, 512, 0, stream>>>(xq, wq, bias, out);
}